// Round 14
// baseline (127.436 us; speedup 1.0000x reference)
//
#include <hip/hip_runtime.h>

#define NB 32
#define NN 256
#define DD 64
#define FMAXV 3.402823466e+38f

// R20: R19 (best, 116.08 = ~78us fixed + ~37us kernel) with the weight
// stream moved SMEM -> VMEM. Diagnosis: R19's 2048 s_load_dwordx4/CU/conv
// thrash the ~16KB scalar K$ (32KB working set) -> L2-latency drains,
// lockstep across waves (~17us/conv). R18 proved the DS-pipe alternative is
// issue-bound (CU-shared: 8.4K ds-ops x 12cyc = 42us ~= measured 43.4).
// VMEM: vector L1 is 32KB/CU (fits both W halves), vmcnt is a SEPARATE
// counter from lgkm (h ds_reads) -> no cross-drain; uniform-address
// global_load_dwordx4 = 1 L1 line broadcast. Forced via R16's pinned-zero
// VGPR offset, but on the ROLLED unroll-4 loop (R16's failure was the
// 64-deep full unroll spilling 512 hoisted loads, not VMEM itself):
// in-flight = 4 h-float4 + 8 w-float4 ~= 48 VGPR + acc 32 -> no spills.
// Ascending-k accumulation preserved (bit-exact).

__device__ __forceinline__ void conv_quad(
    const float* HT, int nq, int d0, const float* Wb, int voff,
    float acc[4][8])
{
#pragma unroll
    for (int r = 0; r < 4; ++r)
#pragma unroll
        for (int c = 0; c < 8; ++c) acc[r][c] = 0.f;
    const float* hp = HT + 4 * nq;
    const float* wp = Wb + d0 + voff;   // voff==0 but VGPR-resident -> VMEM path
#pragma unroll 4
    for (int k = 0; k < DD; ++k) {
        float4 hv = *(const float4*)(hp + k * NN);        // ds_read_b128 (lgkmcnt)
        float4 w0 = *(const float4*)(wp + k * DD);        // global_load_dwordx4 (vmcnt)
        float4 w1 = *(const float4*)(wp + k * DD + 4);    // global_load_dwordx4 (vmcnt)
        const float hr[4] = {hv.x, hv.y, hv.z, hv.w};
        const float wv[8] = {w0.x, w0.y, w0.z, w0.w, w1.x, w1.y, w1.z, w1.w};
#pragma unroll
        for (int r = 0; r < 4; ++r)
#pragma unroll
            for (int c = 0; c < 8; ++c)
                acc[r][c] = fmaf(hr[r], wv[c], acc[r][c]);
    }
}

__global__ __launch_bounds__(1024, 4) void k_all(
    const float* __restrict__ x,
    const float* __restrict__ W1,  const float* __restrict__ b1,
    const float* __restrict__ g1,  const float* __restrict__ beta1,
    const float* __restrict__ We1, const float* __restrict__ be1,
    const float* __restrict__ ge1, const float* __restrict__ bte1,
    const float* __restrict__ We2, const float* __restrict__ be2,
    const float* __restrict__ ge2, const float* __restrict__ bte2,
    const float* __restrict__ Wg1, const float* __restrict__ bg1,
    const float* __restrict__ Wg2, const float* __restrict__ bg2,
    float* __restrict__ out)
{
    __shared__ __align__(16) float HT[DD * NN];   // 64 KB, k-major h
    __shared__ float RMx[DD], RMn[DD];
    __shared__ float xg[2 * DD], hid[DD];

    const int b  = blockIdx.x;
    const int t  = threadIdx.x;
    const int nq = t & 63;                                  // node-quad (lane)
    const int os = __builtin_amdgcn_readfirstlane(t >> 6);  // wave 0..15
    const bool isTi = (os < 8);
    const int d0 = (os & 7) * 8;                            // 8-dim out slice

    int voff = 0;
    asm volatile("" : "+v"(voff));   // runtime-0 VGPR: forces VMEM weight path

    // ========== layer 1: dims 4*os..+3 for nodes 4nq..4nq+3 -> HT ==========
    {
        const int dl = os * 4;
        float hq[4][4];                                     // [u=dim][r=node]
#pragma unroll
        for (int r = 0; r < 4; ++r) {
            float4 xv = *(const float4*)(x + ((size_t)b * NN + 4 * nq + r) * 4);
#pragma unroll
            for (int u = 0; u < 4; ++u) {
                const int d = dl + u;
                float a = b1[d];
                a = fmaf(xv.x, W1[0 * DD + d], a);
                a = fmaf(xv.y, W1[1 * DD + d], a);
                a = fmaf(xv.z, W1[2 * DD + d], a);
                a = fmaf(xv.w, W1[3 * DD + d], a);
                hq[u][r] = g1[d] * fmaxf(a, 0.f) + beta1[d];
            }
        }
#pragma unroll
        for (int u = 0; u < 4; ++u)
            *(float4*)(HT + (dl + u) * NN + 4 * nq) =
                make_float4(hq[u][0], hq[u][1], hq[u][2], hq[u][3]);
    }
    __syncthreads();

    float acc[4][8];

    // ========== conv1 ==========
    conv_quad(HT, nq, d0, isTi ? We1 : (We1 + DD * DD), voff, acc);
    if (!isTi) {   // tj waves: in-register max/min over all 256 nodes
        float mx[8], mn[8];
#pragma unroll
        for (int c = 0; c < 8; ++c) {
            mx[c] = fmaxf(fmaxf(acc[0][c], acc[1][c]), fmaxf(acc[2][c], acc[3][c]));
            mn[c] = fminf(fminf(acc[0][c], acc[1][c]), fminf(acc[2][c], acc[3][c]));
        }
#pragma unroll
        for (int m = 1; m < 64; m <<= 1) {
#pragma unroll
            for (int c = 0; c < 8; ++c) {
                mx[c] = fmaxf(mx[c], __shfl_xor(mx[c], m, 64));
                mn[c] = fminf(mn[c], __shfl_xor(mn[c], m, 64));
            }
        }
        float smx = mx[0], smn = mn[0];
#pragma unroll
        for (int c = 1; c < 8; ++c) {
            smx = (nq == c) ? mx[c] : smx;
            smn = (nq == c) ? mn[c] : smn;
        }
        if (nq < 8) { RMx[d0 + nq] = smx; RMn[d0 + nq] = smn; }
    }
    __syncthreads();   // RM ready; all conv1 HT reads complete

    // ========== conv1 epilogue (ti waves): h2 -> HT ==========
    if (isTi) {
#pragma unroll
        for (int c = 0; c < 8; ++c) {
            const int d = d0 + c;
            const float gv = ge1[d], bv = be1[d], bt = bte1[d];
            const float pick = (gv >= 0.f) ? RMx[d] : RMn[d];
            float4 o;
            o.x = gv * fmaxf(acc[0][c] + pick + bv, 0.f) + bt;
            o.y = gv * fmaxf(acc[1][c] + pick + bv, 0.f) + bt;
            o.z = gv * fmaxf(acc[2][c] + pick + bv, 0.f) + bt;
            o.w = gv * fmaxf(acc[3][c] + pick + bv, 0.f) + bt;
            *(float4*)(HT + d * NN + 4 * nq) = o;
        }
    }
    __syncthreads();   // h2 ready

    // ========== conv2 ==========
    conv_quad(HT, nq, d0, isTi ? We2 : (We2 + DD * DD), voff, acc);
    if (!isTi) {
        float mx[8], mn[8];
#pragma unroll
        for (int c = 0; c < 8; ++c) {
            mx[c] = fmaxf(fmaxf(acc[0][c], acc[1][c]), fmaxf(acc[2][c], acc[3][c]));
            mn[c] = fminf(fminf(acc[0][c], acc[1][c]), fminf(acc[2][c], acc[3][c]));
        }
#pragma unroll
        for (int m = 1; m < 64; m <<= 1) {
#pragma unroll
            for (int c = 0; c < 8; ++c) {
                mx[c] = fmaxf(mx[c], __shfl_xor(mx[c], m, 64));
                mn[c] = fminf(mn[c], __shfl_xor(mn[c], m, 64));
            }
        }
        float smx = mx[0], smn = mn[0];
#pragma unroll
        for (int c = 1; c < 8; ++c) {
            smx = (nq == c) ? mx[c] : smx;
            smn = (nq == c) ? mn[c] : smn;
        }
        if (nq < 8) { RMx[d0 + nq] = smx; RMn[d0 + nq] = smn; }
    }
    __syncthreads();

    // ========== conv2 epilogue + pooling (ti waves) ==========
    if (isTi) {
        float sm[8], mxp[8];
#pragma unroll
        for (int c = 0; c < 8; ++c) {
            const int d = d0 + c;
            const float gv = ge2[d], bv = be2[d], bt = bte2[d];
            const float pick = (gv >= 0.f) ? RMx[d] : RMn[d];
            const float h0 = gv * fmaxf(acc[0][c] + pick + bv, 0.f) + bt;
            const float h1 = gv * fmaxf(acc[1][c] + pick + bv, 0.f) + bt;
            const float h2 = gv * fmaxf(acc[2][c] + pick + bv, 0.f) + bt;
            const float h3 = gv * fmaxf(acc[3][c] + pick + bv, 0.f) + bt;
            sm[c]  = (h0 + h1) + (h2 + h3);
            mxp[c] = fmaxf(fmaxf(h0, h1), fmaxf(h2, h3));
        }
#pragma unroll
        for (int m = 1; m < 64; m <<= 1) {
#pragma unroll
            for (int c = 0; c < 8; ++c) {
                sm[c]  += __shfl_xor(sm[c], m, 64);
                mxp[c]  = fmaxf(mxp[c], __shfl_xor(mxp[c], m, 64));
            }
        }
        float ssm = sm[0], smx = mxp[0];
#pragma unroll
        for (int c = 1; c < 8; ++c) {
            ssm = (nq == c) ? sm[c]  : ssm;
            smx = (nq == c) ? mxp[c] : smx;
        }
        if (nq < 8) {
            xg[d0 + nq]      = ssm * (1.f / 256.f);
            xg[DD + d0 + nq] = smx;
        }
    }
    __syncthreads();

    // ========== head MLP ==========
    if (t < DD) {
        float a = bg1[t];
#pragma unroll
        for (int k = 0; k < 2 * DD; ++k) a = fmaf(xg[k], Wg1[k * DD + t], a);
        hid[t] = fmaxf(a, 0.f);
    }
    __syncthreads();
    if (t < 2) {
        float o = bg2[t];
#pragma unroll
        for (int j = 0; j < DD; ++j) o = fmaf(hid[j], Wg2[j * 2 + t], o);
        out[b * 2 + t] = o;
    }
}

extern "C" void kernel_launch(void* const* d_in, const int* in_sizes, int n_in,
                              void* d_out, int out_size, void* d_ws, size_t ws_size,
                              hipStream_t stream) {
    const float* x     = (const float*)d_in[0];
    const float* W1    = (const float*)d_in[1];
    const float* b1    = (const float*)d_in[2];
    const float* g1    = (const float*)d_in[3];
    const float* beta1 = (const float*)d_in[4];
    const float* We1   = (const float*)d_in[5];
    const float* be1   = (const float*)d_in[6];
    const float* ge1   = (const float*)d_in[7];
    const float* bte1  = (const float*)d_in[8];
    const float* We2   = (const float*)d_in[9];
    const float* be2   = (const float*)d_in[10];
    const float* ge2   = (const float*)d_in[11];
    const float* bte2  = (const float*)d_in[12];
    const float* Wg1   = (const float*)d_in[13];
    const float* bg1   = (const float*)d_in[14];
    const float* Wg2   = (const float*)d_in[15];
    const float* bg2   = (const float*)d_in[16];

    k_all<<<dim3(NB), dim3(1024), 0, stream>>>(
        x, W1, b1, g1, beta1,
        We1, be1, ge1, bte1,
        We2, be2, ge2, bte2,
        Wg1, bg1, Wg2, bg2, (float*)d_out);
}

// Round 15
// 118.848 us; speedup vs baseline: 1.0723x; 1.0723x over previous
//
#include <hip/hip_runtime.h>

#define NB 32
#define NN 256
#define DD 64
#define FMAXV 3.402823466e+38f

// R21: R19 (best, 116.08) with the h stream moved LDS -> GLOBAL (per-batch
// 64KB in ws, L2/L1-resident). Mechanism: R19's k-loop mixed ds_read (h)
// with s_load (weights) -- both in lgkmcnt, SMEM completes out-of-order ->
// full lgkmcnt(0) drains per unroll group. Now h loads are global_load_
// dwordx4 on VMCNT (in-order, partial-waitable -> compiler pipelines deep),
// lgkm counts only the weight s_loads, and all 16 waves read IDENTICAL h
// addresses per k -> L1 broadcast after first touch (h row 1KB/k). h2
// overwrites h1 in place (barrier-separated, element-wise same-thread).
// Weights stay SMEM (best measured: R13/R15/R19 ~37-40 vs DS 43 / VMEM 45+).
// Accumulation order unchanged from R19 (ascending k, same reduce trees).
// ws: hT = 32 x 16384 floats (2MB).

__device__ __forceinline__ void conv_quad(
    const float* hT, int nq, int d0, const float* __restrict__ Wb,
    float acc[4][8])
{
#pragma unroll
    for (int r = 0; r < 4; ++r)
#pragma unroll
        for (int c = 0; c < 8; ++c) acc[r][c] = 0.f;
    const float* hp = hT + 4 * nq;
#pragma unroll 4
    for (int k = 0; k < DD; ++k) {
        float4 hv = *(const float4*)(hp + k * NN);            // global_load_dwordx4 (vmcnt)
        float4 w0 = *(const float4*)(Wb + k * DD + d0);       // s_load_dwordx4 (lgkm)
        float4 w1 = *(const float4*)(Wb + k * DD + d0 + 4);   // s_load_dwordx4 (lgkm)
        const float hr[4] = {hv.x, hv.y, hv.z, hv.w};
        const float wv[8] = {w0.x, w0.y, w0.z, w0.w, w1.x, w1.y, w1.z, w1.w};
#pragma unroll
        for (int r = 0; r < 4; ++r)
#pragma unroll
            for (int c = 0; c < 8; ++c)
                acc[r][c] = fmaf(hr[r], wv[c], acc[r][c]);
    }
}

__global__ __launch_bounds__(1024, 4) void k_all(
    const float* __restrict__ x,
    const float* __restrict__ W1,  const float* __restrict__ b1,
    const float* __restrict__ g1,  const float* __restrict__ beta1,
    const float* __restrict__ We1, const float* __restrict__ be1,
    const float* __restrict__ ge1, const float* __restrict__ bte1,
    const float* __restrict__ We2, const float* __restrict__ be2,
    const float* __restrict__ ge2, const float* __restrict__ bte2,
    const float* __restrict__ Wg1, const float* __restrict__ bg1,
    const float* __restrict__ Wg2, const float* __restrict__ bg2,
    float* __restrict__ hTws,
    float* __restrict__ out)
{
    __shared__ float RMx[DD], RMn[DD];
    __shared__ float xg[2 * DD], hid[DD];

    const int b  = blockIdx.x;
    const int t  = threadIdx.x;
    const int nq = t & 63;                                  // node-quad (lane)
    const int os = __builtin_amdgcn_readfirstlane(t >> 6);  // wave 0..15
    const bool isTi = (os < 8);
    const int d0 = (os & 7) * 8;                            // 8-dim out slice
    float* hT = hTws + (size_t)b * (DD * NN);               // this batch's 64KB h

    // ========== layer 1: dims 4*os..+3 for nodes 4nq..4nq+3 -> hT ==========
    {
        const int dl = os * 4;
        float hq[4][4];                                     // [u=dim][r=node]
#pragma unroll
        for (int r = 0; r < 4; ++r) {
            float4 xv = *(const float4*)(x + ((size_t)b * NN + 4 * nq + r) * 4);
#pragma unroll
            for (int u = 0; u < 4; ++u) {
                const int d = dl + u;
                float a = b1[d];
                a = fmaf(xv.x, W1[0 * DD + d], a);
                a = fmaf(xv.y, W1[1 * DD + d], a);
                a = fmaf(xv.z, W1[2 * DD + d], a);
                a = fmaf(xv.w, W1[3 * DD + d], a);
                hq[u][r] = g1[d] * fmaxf(a, 0.f) + beta1[d];
            }
        }
#pragma unroll
        for (int u = 0; u < 4; ++u)
            *(float4*)(hT + (dl + u) * NN + 4 * nq) =
                make_float4(hq[u][0], hq[u][1], hq[u][2], hq[u][3]);
    }
    __syncthreads();   // drains vmcnt: h1 visible to all waves (same CU)

    float acc[4][8];

    // ========== conv1 ==========
    conv_quad(hT, nq, d0, isTi ? We1 : (We1 + DD * DD), acc);
    if (!isTi) {   // tj waves: in-register max/min over all 256 nodes
        float mx[8], mn[8];
#pragma unroll
        for (int c = 0; c < 8; ++c) {
            mx[c] = fmaxf(fmaxf(acc[0][c], acc[1][c]), fmaxf(acc[2][c], acc[3][c]));
            mn[c] = fminf(fminf(acc[0][c], acc[1][c]), fminf(acc[2][c], acc[3][c]));
        }
#pragma unroll
        for (int m = 1; m < 64; m <<= 1) {
#pragma unroll
            for (int c = 0; c < 8; ++c) {
                mx[c] = fmaxf(mx[c], __shfl_xor(mx[c], m, 64));
                mn[c] = fminf(mn[c], __shfl_xor(mn[c], m, 64));
            }
        }
        float smx = mx[0], smn = mn[0];
#pragma unroll
        for (int c = 1; c < 8; ++c) {
            smx = (nq == c) ? mx[c] : smx;
            smn = (nq == c) ? mn[c] : smn;
        }
        if (nq < 8) { RMx[d0 + nq] = smx; RMn[d0 + nq] = smn; }
    }
    __syncthreads();   // RM ready; all conv1 hT loads complete

    // ========== conv1 epilogue (ti waves): h2 -> hT (in place) ==========
    if (isTi) {
#pragma unroll
        for (int c = 0; c < 8; ++c) {
            const int d = d0 + c;
            const float gv = ge1[d], bv = be1[d], bt = bte1[d];
            const float pick = (gv >= 0.f) ? RMx[d] : RMn[d];
            float4 o;
            o.x = gv * fmaxf(acc[0][c] + pick + bv, 0.f) + bt;
            o.y = gv * fmaxf(acc[1][c] + pick + bv, 0.f) + bt;
            o.z = gv * fmaxf(acc[2][c] + pick + bv, 0.f) + bt;
            o.w = gv * fmaxf(acc[3][c] + pick + bv, 0.f) + bt;
            *(float4*)(hT + d * NN + 4 * nq) = o;
        }
    }
    __syncthreads();   // h2 visible

    // ========== conv2 ==========
    conv_quad(hT, nq, d0, isTi ? We2 : (We2 + DD * DD), acc);
    if (!isTi) {
        float mx[8], mn[8];
#pragma unroll
        for (int c = 0; c < 8; ++c) {
            mx[c] = fmaxf(fmaxf(acc[0][c], acc[1][c]), fmaxf(acc[2][c], acc[3][c]));
            mn[c] = fminf(fminf(acc[0][c], acc[1][c]), fminf(acc[2][c], acc[3][c]));
        }
#pragma unroll
        for (int m = 1; m < 64; m <<= 1) {
#pragma unroll
            for (int c = 0; c < 8; ++c) {
                mx[c] = fmaxf(mx[c], __shfl_xor(mx[c], m, 64));
                mn[c] = fminf(mn[c], __shfl_xor(mn[c], m, 64));
            }
        }
        float smx = mx[0], smn = mn[0];
#pragma unroll
        for (int c = 1; c < 8; ++c) {
            smx = (nq == c) ? mx[c] : smx;
            smn = (nq == c) ? mn[c] : smn;
        }
        if (nq < 8) { RMx[d0 + nq] = smx; RMn[d0 + nq] = smn; }
    }
    __syncthreads();

    // ========== conv2 epilogue + pooling (ti waves) ==========
    if (isTi) {
        float sm[8], mxp[8];
#pragma unroll
        for (int c = 0; c < 8; ++c) {
            const int d = d0 + c;
            const float gv = ge2[d], bv = be2[d], bt = bte2[d];
            const float pick = (gv >= 0.f) ? RMx[d] : RMn[d];
            const float h0 = gv * fmaxf(acc[0][c] + pick + bv, 0.f) + bt;
            const float h1 = gv * fmaxf(acc[1][c] + pick + bv, 0.f) + bt;
            const float h2 = gv * fmaxf(acc[2][c] + pick + bv, 0.f) + bt;
            const float h3 = gv * fmaxf(acc[3][c] + pick + bv, 0.f) + bt;
            sm[c]  = (h0 + h1) + (h2 + h3);
            mxp[c] = fmaxf(fmaxf(h0, h1), fmaxf(h2, h3));
        }
#pragma unroll
        for (int m = 1; m < 64; m <<= 1) {
#pragma unroll
            for (int c = 0; c < 8; ++c) {
                sm[c]  += __shfl_xor(sm[c], m, 64);
                mxp[c]  = fmaxf(mxp[c], __shfl_xor(mxp[c], m, 64));
            }
        }
        float ssm = sm[0], smx = mxp[0];
#pragma unroll
        for (int c = 1; c < 8; ++c) {
            ssm = (nq == c) ? sm[c]  : ssm;
            smx = (nq == c) ? mxp[c] : smx;
        }
        if (nq < 8) {
            xg[d0 + nq]      = ssm * (1.f / 256.f);
            xg[DD + d0 + nq] = smx;
        }
    }
    __syncthreads();

    // ========== head MLP ==========
    if (t < DD) {
        float a = bg1[t];
#pragma unroll
        for (int k = 0; k < 2 * DD; ++k) a = fmaf(xg[k], Wg1[k * DD + t], a);
        hid[t] = fmaxf(a, 0.f);
    }
    __syncthreads();
    if (t < 2) {
        float o = bg2[t];
#pragma unroll
        for (int j = 0; j < DD; ++j) o = fmaf(hid[j], Wg2[j * 2 + t], o);
        out[b * 2 + t] = o;
    }
}

extern "C" void kernel_launch(void* const* d_in, const int* in_sizes, int n_in,
                              void* d_out, int out_size, void* d_ws, size_t ws_size,
                              hipStream_t stream) {
    const float* x     = (const float*)d_in[0];
    const float* W1    = (const float*)d_in[1];
    const float* b1    = (const float*)d_in[2];
    const float* g1    = (const float*)d_in[3];
    const float* beta1 = (const float*)d_in[4];
    const float* We1   = (const float*)d_in[5];
    const float* be1   = (const float*)d_in[6];
    const float* ge1   = (const float*)d_in[7];
    const float* bte1  = (const float*)d_in[8];
    const float* We2   = (const float*)d_in[9];
    const float* be2   = (const float*)d_in[10];
    const float* ge2   = (const float*)d_in[11];
    const float* bte2  = (const float*)d_in[12];
    const float* Wg1   = (const float*)d_in[13];
    const float* bg1   = (const float*)d_in[14];
    const float* Wg2   = (const float*)d_in[15];
    const float* bg2   = (const float*)d_in[16];

    k_all<<<dim3(NB), dim3(1024), 0, stream>>>(
        x, W1, b1, g1, beta1,
        We1, be1, ge1, bte1,
        We2, be2, ge2, bte2,
        Wg1, bg1, Wg2, bg2,
        (float*)d_ws, (float*)d_out);
}